// Round 1
// baseline (3671.568 us; speedup 1.0000x reference)
//
#include <hip/hip_runtime.h>
#include <hip/hip_bf16.h>

#define N_NODES 131072
#define N_EDGES 524288
#define F_IN 16
#define DIM 64
#define DNN 16
#define BK 4
#define NG 8192
#define N_ITERS 8   // NL1*NL2

// ---------------- degree / inverse count ----------------
__global__ __launch_bounds__(256) void k_degree(const int* __restrict__ ei, float* __restrict__ cnt) {
    int e = blockIdx.x * 256 + threadIdx.x;
    atomicAdd(&cnt[ei[N_EDGES + e]], 1.0f);
}

__global__ __launch_bounds__(256) void k_invcnt(float* __restrict__ cnt) {
    int i = blockIdx.x * 256 + threadIdx.x;
    cnt[i] = 1.0f / fmaxf(cnt[i], 1.0f);
}

// ---------------- init: h = relu(x @ lin0_w + lin0_b) ----------------
__global__ __launch_bounds__(256) void k_init(const float* __restrict__ x, const float* __restrict__ w,
                                              const float* __restrict__ b, float* __restrict__ h) {
    __shared__ float s_w[F_IN * DIM];   // 16x64
    int tid = threadIdx.x;
    for (int idx = tid; idx < F_IN * DIM; idx += 256) s_w[idx] = w[idx];
    __syncthreads();
    int gid = blockIdx.x * 256 + tid;
    int i = gid >> 6;            // node (same across the 64-lane wave)
    int c = gid & 63;            // output channel == lane
    int lane = tid & 63;
    float xv = x[i * F_IN + (lane & 15)];
    float acc = b[c];
#pragma unroll
    for (int k = 0; k < F_IN; ++k) acc += __shfl(xv, k, 64) * s_w[k * DIM + c];
    h[gid] = fmaxf(acc, 0.0f);
}

// ---------------- out1 = h @ lin1_w + lin1_b  (N x 64 -> N x 16) ----------------
__global__ __launch_bounds__(256) void k_lin1(const float* __restrict__ h, const float* __restrict__ w,
                                              const float* __restrict__ b, float* __restrict__ out1) {
    __shared__ float s_w[DIM * DNN];    // 64x16
    __shared__ float s_h[16 * 65];      // 16 nodes, padded stride 65
    int tid = threadIdx.x;
    for (int idx = tid; idx < DIM * DNN; idx += 256) s_w[idx] = w[idx];
    int nb = blockIdx.x * 16;
    for (int idx = tid; idx < 16 * 64; idx += 256) {
        int nl = idx >> 6, k = idx & 63;
        s_h[nl * 65 + k] = h[(nb + nl) * DIM + k];
    }
    __syncthreads();
    int nl = tid >> 4, c = tid & 15;
    float acc = b[c];
#pragma unroll
    for (int k = 0; k < DIM; ++k) acc += s_h[nl * 65 + k] * s_w[k * DNN + c];
    out1[nb * DNN + tid] = acc;
}

// ---------------- edge: msg = out1[src] @ W_e ; atomic scatter to aggr[dst] ----------------
__global__ __launch_bounds__(256) void k_edge(const float* __restrict__ out1, const float* __restrict__ ea,
                                              const int* __restrict__ ei, const float* __restrict__ nn1w,
                                              const float* __restrict__ nn1b, float* __restrict__ aggr) {
    __shared__ float s_w[BK * 256];
    __shared__ float s_b[256];
    int tid = threadIdx.x;
    for (int idx = tid; idx < BK * 256; idx += 256) s_w[idx] = nn1w[idx];
    s_b[tid] = nn1b[tid];
    __syncthreads();
    int g = blockIdx.x * 256 + tid;
    int e = g >> 4;       // 16 lanes per edge
    int o = g & 15;       // output channel
    int src = ei[e];
    int dst = ei[N_EDGES + e];
    float a0 = ea[e * 4 + 0], a1 = ea[e * 4 + 1], a2 = ea[e * 4 + 2], a3 = ea[e * 4 + 3];
    int lane = tid & 63;
    int base = lane & 48;                 // start of this edge's 16-lane group
    float xin = out1[src * DNN + o];      // lane (base+k) holds out1[src][k]
    float msg = 0.0f;
#pragma unroll
    for (int k = 0; k < DNN; ++k) {
        int wi = k * 16 + o;
        float w = s_b[wi] + a0 * s_w[wi] + a1 * s_w[256 + wi] + a2 * s_w[512 + wi] + a3 * s_w[768 + wi];
        msg += __shfl(xin, base + k, 64) * w;
    }
    atomicAdd(&aggr[dst * DNN + o], msg);
}

// ---------------- node: out2 = out1@root_w + aggr*inv + conv_b ; GRU update of h ----------------
__global__ __launch_bounds__(256) void k_node(const float* __restrict__ out1, const float* __restrict__ aggr,
                                              const float* __restrict__ inv_cnt, float* __restrict__ h,
                                              const float* __restrict__ root_w, const float* __restrict__ conv_b,
                                              const float* __restrict__ wih, const float* __restrict__ whh,
                                              const float* __restrict__ bih, const float* __restrict__ bhh) {
    __shared__ float s_ih[DNN * 193];   // transposed [16][192] padded -> 12.35 KB
    __shared__ float s_hh[DIM * 193];   // transposed [64][192] padded -> 49.4 KB
    int tid = threadIdx.x;
    for (int idx = tid; idx < 192 * DNN; idx += 256) {
        int row = idx >> 4, k = idx & 15;
        s_ih[k * 193 + row] = wih[idx];
    }
    for (int idx = tid; idx < 192 * DIM; idx += 256) {
        int row = idx >> 6, j = idx & 63;
        s_hh[j * 193 + row] = whh[idx];
    }
    __syncthreads();
    int lane = tid & 63;
    int wid = blockIdx.x * 4 + (tid >> 6);
    int nwaves = gridDim.x * 4;
    // per-lane constants
    float rw[16];
#pragma unroll
    for (int k = 0; k < 16; ++k) rw[k] = root_w[k * 16 + (lane & 15)];
    float cb  = conv_b[lane & 15];
    float b_r = bih[lane] + bhh[lane];
    float b_z = bih[64 + lane] + bhh[64 + lane];
    float bni = bih[128 + lane];
    float bnh = bhh[128 + lane];
    for (int i = wid; i < N_NODES; i += nwaves) {
        float xin = out1[i * DNN + (lane & 15)];
        float hv  = h[i * DIM + lane];
        float inv = inv_cnt[i];
        float ag  = aggr[i * DNN + (lane & 15)];
        // out2 (meaningful in lanes 0..15)
        float o2 = cb + ag * inv;
#pragma unroll
        for (int k = 0; k < 16; ++k) o2 += rw[k] * __shfl(xin, k, 64);
        // gates
        float gr = b_r, gz = b_z, gni = bni, gnh = bnh;
#pragma unroll
        for (int j = 0; j < 16; ++j) {
            float o2j = __shfl(o2, j, 64);
            gr  += o2j * s_ih[j * 193 + lane];
            gz  += o2j * s_ih[j * 193 + 64 + lane];
            gni += o2j * s_ih[j * 193 + 128 + lane];
        }
#pragma unroll
        for (int j = 0; j < 64; ++j) {
            float hj = __shfl(hv, j, 64);
            gr  += hj * s_hh[j * 193 + lane];
            gz  += hj * s_hh[j * 193 + 64 + lane];
            gnh += hj * s_hh[j * 193 + 128 + lane];
        }
        float r = 1.0f / (1.0f + expf(-gr));
        float z = 1.0f / (1.0f + expf(-gz));
        float nc = tanhf(gni + r * gnh);
        h[i * DIM + lane] = (1.0f - z) * nc + z * hv;
    }
}

// ---------------- final: y = h @ lin2_w ; pooled = segment_sum(y, batch) ----------------
__global__ __launch_bounds__(256) void k_final(const float* __restrict__ h, const float* __restrict__ w2,
                                               const int* __restrict__ batch, float* __restrict__ out) {
    int i = blockIdx.x * 4 + (threadIdx.x >> 6);
    int lane = threadIdx.x & 63;
    float v = h[i * DIM + lane] * w2[lane];
#pragma unroll
    for (int off = 32; off > 0; off >>= 1) v += __shfl_down(v, off, 64);
    if (lane == 0) atomicAdd(&out[batch[i]], v);
}

extern "C" void kernel_launch(void* const* d_in, const int* in_sizes, int n_in,
                              void* d_out, int out_size, void* d_ws, size_t ws_size,
                              hipStream_t stream) {
    const float* x        = (const float*)d_in[0];
    const float* edge_attr= (const float*)d_in[1];
    const float* lin0_w   = (const float*)d_in[2];
    const float* lin0_b   = (const float*)d_in[3];
    const float* nn1_w    = (const float*)d_in[4];
    const float* nn1_b    = (const float*)d_in[5];
    const float* root_w   = (const float*)d_in[6];
    const float* conv_b   = (const float*)d_in[7];
    const float* gru_w_ih = (const float*)d_in[8];
    const float* gru_w_hh = (const float*)d_in[9];
    const float* gru_b_ih = (const float*)d_in[10];
    const float* gru_b_hh = (const float*)d_in[11];
    const float* lin1_w   = (const float*)d_in[12];
    const float* lin1_b   = (const float*)d_in[13];
    const float* lin2_w   = (const float*)d_in[14];
    const int*   ei       = (const int*)d_in[15];
    const int*   batch    = (const int*)d_in[16];
    float* out = (float*)d_out;

    // workspace layout (f32): h[N*64] | out1[N*16] | aggr[N*16] | inv_cnt[N]
    char* ws = (char*)d_ws;
    float* h       = (float*)(ws);
    float* out1    = (float*)(ws + (size_t)N_NODES * DIM * 4);
    float* aggr    = (float*)(ws + (size_t)N_NODES * DIM * 4 + (size_t)N_NODES * DNN * 4);
    float* inv_cnt = (float*)(ws + (size_t)N_NODES * DIM * 4 + 2ull * N_NODES * DNN * 4);

    hipMemsetAsync(d_out, 0, (size_t)NG * 4, stream);
    hipMemsetAsync(inv_cnt, 0, (size_t)N_NODES * 4, stream);
    k_degree<<<N_EDGES / 256, 256, 0, stream>>>(ei, inv_cnt);
    k_invcnt<<<N_NODES / 256, 256, 0, stream>>>(inv_cnt);
    k_init<<<N_NODES * DIM / 256, 256, 0, stream>>>(x, lin0_w, lin0_b, h);

    for (int it = 0; it < N_ITERS; ++it) {
        int j = it >> 1;   // GRU index (NL2 = 2)
        k_lin1<<<N_NODES / 16, 256, 0, stream>>>(h, lin1_w, lin1_b, out1);
        hipMemsetAsync(aggr, 0, (size_t)N_NODES * DNN * 4, stream);
        k_edge<<<N_EDGES * 16 / 256, 256, 0, stream>>>(out1, edge_attr, ei, nn1_w, nn1_b, aggr);
        k_node<<<2048, 256, 0, stream>>>(out1, aggr, inv_cnt, h, root_w, conv_b,
                                         gru_w_ih + (size_t)j * 192 * DNN,
                                         gru_w_hh + (size_t)j * 192 * DIM,
                                         gru_b_ih + (size_t)j * 192,
                                         gru_b_hh + (size_t)j * 192);
    }
    k_final<<<N_NODES / 4, 256, 0, stream>>>(h, lin2_w, batch, out);
}

// Round 2
// 1581.527 us; speedup vs baseline: 2.3215x; 2.3215x over previous
//
#include <hip/hip_runtime.h>
#include <hip/hip_bf16.h>

#define N_NODES 131072
#define N_EDGES 524288
#define F_IN 16
#define DIM 64
#define DNN 16
#define BK 4
#define NG 8192
#define N_ITERS 8   // NL1*NL2

// ---------------- degree / inverse count ----------------
__global__ __launch_bounds__(256) void k_degree(const int* __restrict__ ei, float* __restrict__ cnt) {
    int e = blockIdx.x * 256 + threadIdx.x;
    atomicAdd(&cnt[ei[N_EDGES + e]], 1.0f);
}

__global__ __launch_bounds__(256) void k_invcnt(float* __restrict__ cnt) {
    int i = blockIdx.x * 256 + threadIdx.x;
    cnt[i] = 1.0f / fmaxf(cnt[i], 1.0f);
}

// ---------------- init: h = relu(x @ lin0_w + lin0_b) ----------------
__global__ __launch_bounds__(256) void k_init(const float* __restrict__ x, const float* __restrict__ w,
                                              const float* __restrict__ b, float* __restrict__ h) {
    __shared__ float s_w[F_IN * DIM];   // 16x64
    int tid = threadIdx.x;
    for (int idx = tid; idx < F_IN * DIM; idx += 256) s_w[idx] = w[idx];
    __syncthreads();
    int gid = blockIdx.x * 256 + tid;
    int i = gid >> 6;            // node (same across the 64-lane wave)
    int c = gid & 63;            // output channel == lane
    int lane = tid & 63;
    float xv = x[i * F_IN + (lane & 15)];
    float acc = b[c];
#pragma unroll
    for (int k = 0; k < F_IN; ++k) acc += __shfl(xv, k, 64) * s_w[k * DIM + c];
    h[gid] = fmaxf(acc, 0.0f);
}

// ---------------- out1 = h @ lin1_w + lin1_b  (N x 64 -> N x 16) ----------------
__global__ __launch_bounds__(256) void k_lin1(const float* __restrict__ h, const float* __restrict__ w,
                                              const float* __restrict__ b, float* __restrict__ out1) {
    __shared__ float s_w[DIM * DNN];    // 64x16
    __shared__ float s_h[16 * 65];      // 16 nodes, padded stride 65
    int tid = threadIdx.x;
    for (int idx = tid; idx < DIM * DNN; idx += 256) s_w[idx] = w[idx];
    int nb = blockIdx.x * 16;
    for (int idx = tid; idx < 16 * 64; idx += 256) {
        int nl = idx >> 6, k = idx & 63;
        s_h[nl * 65 + k] = h[(nb + nl) * DIM + k];
    }
    __syncthreads();
    int nl = tid >> 4, c = tid & 15;
    float acc = b[c];
#pragma unroll
    for (int k = 0; k < DIM; ++k) acc += s_h[nl * 65 + k] * s_w[k * DNN + c];
    out1[nb * DNN + tid] = acc;
}

// ---------------- edge: msg = out1[src] @ W_e ; atomic scatter to aggr[dst] ----------------
__global__ __launch_bounds__(256) void k_edge(const float* __restrict__ out1, const float* __restrict__ ea,
                                              const int* __restrict__ ei, const float* __restrict__ nn1w,
                                              const float* __restrict__ nn1b, float* __restrict__ aggr) {
    __shared__ float s_w[BK * 256];
    __shared__ float s_b[256];
    int tid = threadIdx.x;
    for (int idx = tid; idx < BK * 256; idx += 256) s_w[idx] = nn1w[idx];
    s_b[tid] = nn1b[tid];
    __syncthreads();
    int g = blockIdx.x * 256 + tid;
    int e = g >> 4;       // 16 lanes per edge
    int o = g & 15;       // output channel
    int src = ei[e];
    int dst = ei[N_EDGES + e];
    float a0 = ea[e * 4 + 0], a1 = ea[e * 4 + 1], a2 = ea[e * 4 + 2], a3 = ea[e * 4 + 3];
    int lane = tid & 63;
    int base = lane & 48;                 // start of this edge's 16-lane group
    float xin = out1[src * DNN + o];      // lane (base+k) holds out1[src][k]
    float msg = 0.0f;
#pragma unroll
    for (int k = 0; k < DNN; ++k) {
        int wi = k * 16 + o;
        float w = s_b[wi] + a0 * s_w[wi] + a1 * s_w[256 + wi] + a2 * s_w[512 + wi] + a3 * s_w[768 + wi];
        msg += __shfl(xin, base + k, 64) * w;
    }
    atomicAdd(&aggr[dst * DNN + o], msg);
}

// ---------------- node: register-blocked GEMM GRU ----------------
// block = 64 nodes, 256 threads = 16 node-groups (ng) x 16 col-groups (cg)
// thread tile: 4 nodes x 12 cols (cols c = cg+16j, j=0..11 -> j<4:r, 4..7:z, 8..11:n)
__global__ __launch_bounds__(256, 2) void k_node(const float* __restrict__ out1, const float* __restrict__ aggr,
                                              const float* __restrict__ inv_cnt, float* __restrict__ h,
                                              const float* __restrict__ root_w, const float* __restrict__ conv_b,
                                              const float* __restrict__ wih, const float* __restrict__ whh,
                                              const float* __restrict__ bih, const float* __restrict__ bhh) {
    __shared__ float s_whh[64 * 193];   // [k][c] transposed, stride 193 -> conflict-free r/w
    __shared__ float s_wih[16 * 192];   // [k][c] transposed
    int tid = threadIdx.x;
    for (int idx = tid; idx < 192 * DIM; idx += 256) {
        int c = idx >> 6, k = idx & 63;
        s_whh[k * 193 + c] = whh[idx];          // global coalesced, LDS banks (k+c)%32 -> 2-way (free)
    }
    for (int idx = tid; idx < 192 * DNN; idx += 256) {
        int c = idx >> 4, k = idx & 15;
        s_wih[k * 192 + c] = wih[idx];
    }
    int cg = tid & 15, ng = tid >> 4;
    int lane = tid & 63;
    int lbase = lane & 48;                      // lanes sharing node-group
    // persistent per-thread constants
    float rw[16], br[4], bz[4], bni[4], bnh[4];
#pragma unroll
    for (int k = 0; k < 16; ++k) rw[k] = root_w[k * 16 + cg];
#pragma unroll
    for (int j = 0; j < 4; ++j) {
        int c = cg + 16 * j;
        br[j]  = bih[c] + bhh[c];
        bz[j]  = bih[64 + c] + bhh[64 + c];
        bni[j] = bih[128 + c];
        bnh[j] = bhh[128 + c];
    }
    float cb = conv_b[cg];
    __syncthreads();

    int nb = blockIdx.x * 64;
    // h tile + out2 in registers
    float h_[4][4], o2[4];
#pragma unroll
    for (int m = 0; m < 4; ++m) {
        int node = nb + 4 * ng + m;
#pragma unroll
        for (int jj = 0; jj < 4; ++jj) h_[m][jj] = h[node * 64 + cg + 16 * jj];
        float o1  = out1[node * 16 + cg];
        float acc = cb + aggr[node * 16 + cg] * inv_cnt[node];
#pragma unroll
        for (int k = 0; k < 16; ++k) acc += rw[k] * __shfl(o1, lbase + k, 64);
        o2[m] = acc;
    }

    float accr[4][4] = {}, accz[4][4] = {}, accni[4][4] = {}, accnh[4][4] = {};
    // ih GEMM: gates += out2 @ wih^T
#pragma unroll
    for (int k = 0; k < 16; ++k) {
        float o2k[4];
#pragma unroll
        for (int m = 0; m < 4; ++m) o2k[m] = __shfl(o2[m], lbase + k, 64);
#pragma unroll
        for (int j = 0; j < 4; ++j) {
            float wr = s_wih[k * 192 + cg + 16 * j];
            float wz = s_wih[k * 192 + 64 + cg + 16 * j];
            float wn = s_wih[k * 192 + 128 + cg + 16 * j];
#pragma unroll
            for (int m = 0; m < 4; ++m) {
                accr[m][j] += o2k[m] * wr;
                accz[m][j] += o2k[m] * wz;
                accni[m][j] += o2k[m] * wn;
            }
        }
    }
    // hh GEMM: gates += h @ whh^T
#pragma unroll
    for (int jj = 0; jj < 4; ++jj) {
#pragma unroll
        for (int dk = 0; dk < 16; ++dk) {
            int d = 16 * jj + dk;
            float hv[4];
#pragma unroll
            for (int m = 0; m < 4; ++m) hv[m] = __shfl(h_[m][jj], lbase + dk, 64);
#pragma unroll
            for (int j = 0; j < 4; ++j) {
                float wr = s_whh[d * 193 + cg + 16 * j];
                float wz = s_whh[d * 193 + 64 + cg + 16 * j];
                float wn = s_whh[d * 193 + 128 + cg + 16 * j];
#pragma unroll
                for (int m = 0; m < 4; ++m) {
                    accr[m][j] += hv[m] * wr;
                    accz[m][j] += hv[m] * wz;
                    accnh[m][j] += hv[m] * wn;
                }
            }
        }
    }
    // epilogue: GRU elementwise, write h
#pragma unroll
    for (int m = 0; m < 4; ++m) {
        int node = nb + 4 * ng + m;
#pragma unroll
        for (int j = 0; j < 4; ++j) {
            float r = 1.0f / (1.0f + __expf(-(accr[m][j] + br[j])));
            float z = 1.0f / (1.0f + __expf(-(accz[m][j] + bz[j])));
            float x2 = accni[m][j] + bni[j] + r * (accnh[m][j] + bnh[j]);
            float ax = fabsf(x2);
            float e  = __expf(-2.0f * ax);
            float nc = __builtin_copysignf((1.0f - e) / (1.0f + e), x2);
            h[node * 64 + cg + 16 * j] = (1.0f - z) * nc + z * h_[m][j];
        }
    }
}

// ---------------- final: y = h @ lin2_w ; pooled = segment_sum(y, batch) ----------------
__global__ __launch_bounds__(256) void k_final(const float* __restrict__ h, const float* __restrict__ w2,
                                               const int* __restrict__ batch, float* __restrict__ out) {
    int i = blockIdx.x * 4 + (threadIdx.x >> 6);
    int lane = threadIdx.x & 63;
    float v = h[i * DIM + lane] * w2[lane];
#pragma unroll
    for (int off = 32; off > 0; off >>= 1) v += __shfl_down(v, off, 64);
    if (lane == 0) atomicAdd(&out[batch[i]], v);
}

extern "C" void kernel_launch(void* const* d_in, const int* in_sizes, int n_in,
                              void* d_out, int out_size, void* d_ws, size_t ws_size,
                              hipStream_t stream) {
    const float* x        = (const float*)d_in[0];
    const float* edge_attr= (const float*)d_in[1];
    const float* lin0_w   = (const float*)d_in[2];
    const float* lin0_b   = (const float*)d_in[3];
    const float* nn1_w    = (const float*)d_in[4];
    const float* nn1_b    = (const float*)d_in[5];
    const float* root_w   = (const float*)d_in[6];
    const float* conv_b   = (const float*)d_in[7];
    const float* gru_w_ih = (const float*)d_in[8];
    const float* gru_w_hh = (const float*)d_in[9];
    const float* gru_b_ih = (const float*)d_in[10];
    const float* gru_b_hh = (const float*)d_in[11];
    const float* lin1_w   = (const float*)d_in[12];
    const float* lin1_b   = (const float*)d_in[13];
    const float* lin2_w   = (const float*)d_in[14];
    const int*   ei       = (const int*)d_in[15];
    const int*   batch    = (const int*)d_in[16];
    float* out = (float*)d_out;

    // workspace layout (f32): h[N*64] | out1[N*16] | aggr[N*16] | inv_cnt[N]
    char* ws = (char*)d_ws;
    float* h       = (float*)(ws);
    float* out1    = (float*)(ws + (size_t)N_NODES * DIM * 4);
    float* aggr    = (float*)(ws + (size_t)N_NODES * DIM * 4 + (size_t)N_NODES * DNN * 4);
    float* inv_cnt = (float*)(ws + (size_t)N_NODES * DIM * 4 + 2ull * N_NODES * DNN * 4);

    hipMemsetAsync(d_out, 0, (size_t)NG * 4, stream);
    hipMemsetAsync(inv_cnt, 0, (size_t)N_NODES * 4, stream);
    k_degree<<<N_EDGES / 256, 256, 0, stream>>>(ei, inv_cnt);
    k_invcnt<<<N_NODES / 256, 256, 0, stream>>>(inv_cnt);
    k_init<<<N_NODES * DIM / 256, 256, 0, stream>>>(x, lin0_w, lin0_b, h);

    for (int it = 0; it < N_ITERS; ++it) {
        int j = it >> 1;   // GRU index (NL2 = 2)
        k_lin1<<<N_NODES / 16, 256, 0, stream>>>(h, lin1_w, lin1_b, out1);
        hipMemsetAsync(aggr, 0, (size_t)N_NODES * DNN * 4, stream);
        k_edge<<<N_EDGES * 16 / 256, 256, 0, stream>>>(out1, edge_attr, ei, nn1_w, nn1_b, aggr);
        k_node<<<N_NODES / 64, 256, 0, stream>>>(out1, aggr, inv_cnt, h, root_w, conv_b,
                                         gru_w_ih + (size_t)j * 192 * DNN,
                                         gru_w_hh + (size_t)j * 192 * DIM,
                                         gru_b_ih + (size_t)j * 192,
                                         gru_b_hh + (size_t)j * 192);
    }
    k_final<<<N_NODES / 4, 256, 0, stream>>>(h, lin2_w, batch, out);
}

// Round 4
// 1134.479 us; speedup vs baseline: 3.2363x; 1.3941x over previous
//
#include <hip/hip_runtime.h>
#include <hip/hip_bf16.h>

#define N_NODES 131072
#define N_EDGES 524288
#define F_IN 16
#define DIM 64
#define DNN 16
#define BK 4
#define NG 8192
#define N_ITERS 8   // NL1*NL2

#define FMA4(A_, S_, W_) { (A_).x = fmaf((S_), (W_).x, (A_).x); (A_).y = fmaf((S_), (W_).y, (A_).y); \
                           (A_).z = fmaf((S_), (W_).z, (A_).z); (A_).w = fmaf((S_), (W_).w, (A_).w); }

// ---------------- degree / inverse count ----------------
__global__ __launch_bounds__(256) void k_degree(const int* __restrict__ ei, float* __restrict__ cnt) {
    int e = blockIdx.x * 256 + threadIdx.x;
    atomicAdd(&cnt[ei[N_EDGES + e]], 1.0f);
}

__global__ __launch_bounds__(256) void k_invcnt(float* __restrict__ cnt) {
    int i = blockIdx.x * 256 + threadIdx.x;
    cnt[i] = 1.0f / fmaxf(cnt[i], 1.0f);
}

// ---------------- init: h = relu(x @ lin0_w + lin0_b) ----------------
__global__ __launch_bounds__(256) void k_init(const float* __restrict__ x, const float* __restrict__ w,
                                              const float* __restrict__ b, float* __restrict__ h) {
    __shared__ float s_w[F_IN * DIM];   // 16x64
    int tid = threadIdx.x;
    for (int idx = tid; idx < F_IN * DIM; idx += 256) s_w[idx] = w[idx];
    __syncthreads();
    int gid = blockIdx.x * 256 + tid;
    int i = gid >> 6;            // node
    int c = gid & 63;            // output channel == lane
    int lane = tid & 63;
    float xv = x[i * F_IN + (lane & 15)];
    float acc = b[c];
#pragma unroll
    for (int k = 0; k < F_IN; ++k) acc += __shfl(xv, k, 64) * s_w[k * DIM + c];
    h[gid] = fmaxf(acc, 0.0f);
}

// ---------------- out1 = h @ lin1_w + lin1_b ; also zero aggr ----------------
__global__ __launch_bounds__(256) void k_lin1(const float* __restrict__ h, const float* __restrict__ w,
                                              const float* __restrict__ b, float* __restrict__ out1,
                                              float* __restrict__ aggr) {
    __shared__ float s_h[64 * 68];      // 64 nodes x 64 q, stride 68
    int tid = threadIdx.x;
    int nb = blockIdx.x * 64;
    const float4* hp = (const float4*)(h + (size_t)nb * 64);
    for (int i = tid; i < 64 * 16; i += 256) {
        int n = i >> 4, q4 = i & 15;
        float4 v = hp[i];
        *(float4*)&s_h[n * 68 + q4 * 4] = v;
    }
    int ct = tid & 15;
    float wcol[64];
#pragma unroll
    for (int q = 0; q < 64; ++q) wcol[q] = w[q * 16 + ct];
    float bias = b[ct];
    ((float4*)(aggr + (size_t)nb * 16))[tid] = make_float4(0.f, 0.f, 0.f, 0.f);
    __syncthreads();
    int ng = tid >> 4;
#pragma unroll
    for (int rep = 0; rep < 4; ++rep) {
        int nl = ng + 16 * rep;
        float acc = bias;
#pragma unroll
        for (int q4 = 0; q4 < 16; ++q4) {
            float4 hv = *(const float4*)&s_h[nl * 68 + q4 * 4];
            acc = fmaf(hv.x, wcol[4 * q4 + 0], acc);
            acc = fmaf(hv.y, wcol[4 * q4 + 1], acc);
            acc = fmaf(hv.z, wcol[4 * q4 + 2], acc);
            acc = fmaf(hv.w, wcol[4 * q4 + 3], acc);
        }
        out1[(size_t)(nb + nl) * 16 + ct] = acc;
    }
}

// ---------------- edge: register-cached W columns, grid-stride over edges ----------------
__global__ __launch_bounds__(256, 3) void k_edge(const float* __restrict__ out1, const float* __restrict__ ea,
                                                 const int* __restrict__ ei, const float* __restrict__ nn1w,
                                                 const float* __restrict__ nn1b, float* __restrict__ aggr) {
    int tid = threadIdx.x;
    int o = tid & 15;
    float w0[16], w1[16], w2[16], w3[16], bs[16];
#pragma unroll
    for (int k = 0; k < 16; ++k) {
        int wi = k * 16 + o;
        bs[k] = nn1b[wi];
        w0[k] = nn1w[wi];
        w1[k] = nn1w[256 + wi];
        w2[k] = nn1w[512 + wi];
        w3[k] = nn1w[768 + wi];
    }
    int eg = blockIdx.x * 16 + (tid >> 4);
    int estride = gridDim.x * 16;
    for (int e = eg; e < N_EDGES; e += estride) {
        int src = ei[e];
        int dst = ei[N_EDGES + e];
        const float4* xp = (const float4*)(out1 + (size_t)src * 16);
        float4 x0 = xp[0], x1 = xp[1], x2 = xp[2], x3 = xp[3];
        float4 a = ((const float4*)ea)[e];
        float xa[16] = {x0.x, x0.y, x0.z, x0.w, x1.x, x1.y, x1.z, x1.w,
                        x2.x, x2.y, x2.z, x2.w, x3.x, x3.y, x3.z, x3.w};
        float msg = 0.f;
#pragma unroll
        for (int k = 0; k < 16; ++k) {
            float wv = bs[k];
            wv = fmaf(a.x, w0[k], wv);
            wv = fmaf(a.y, w1[k], wv);
            wv = fmaf(a.z, w2[k], wv);
            wv = fmaf(a.w, w3[k], wv);
            msg = fmaf(xa[k], wv, msg);
        }
        atomicAdd(&aggr[(size_t)dst * 16 + o], msg);
    }
}

// ---------------- node: m=8 register-blocked GEMM GRU, b128 weight reads ----------------
// 256 threads = 16 ng x 16 cg; thread: nodes n0..n0+7, cols cg+16j (j=0..3), 3 gates
// LDS layout: word = d*196 + g*64 + cg*4 + j   for weight[c = g*64 + cg + 16*j][d]
__global__ __launch_bounds__(256, 2) void k_node(const float* __restrict__ out1, const float* __restrict__ aggr,
                                              const float* __restrict__ inv_cnt, float* __restrict__ h,
                                              const float* __restrict__ root_w, const float* __restrict__ conv_b,
                                              const float* __restrict__ wih, const float* __restrict__ whh,
                                              const float* __restrict__ bih, const float* __restrict__ bhh) {
    __shared__ float s_whh[64 * 196];   // 50.2 KB
    __shared__ float s_wih[16 * 196];   // 12.5 KB
    int tid = threadIdx.x;
    for (int idx = tid; idx < 192 * 64; idx += 256) {
        int c = idx >> 6, d = idx & 63;
        int g = c >> 6, r = c & 63, cgw = r & 15, jw = r >> 4;
        s_whh[d * 196 + g * 64 + cgw * 4 + jw] = whh[idx];
    }
    for (int idx = tid; idx < 192 * 16; idx += 256) {
        int c = idx >> 4, k = idx & 15;
        int g = c >> 6, r = c & 63, cgw = r & 15, jw = r >> 4;
        s_wih[k * 196 + g * 64 + cgw * 4 + jw] = wih[idx];
    }
    int cg = tid & 15, ng = tid >> 4;
    int lane = tid & 63, lbase = lane & 48;
    float rw[16];
#pragma unroll
    for (int k = 0; k < 16; ++k) rw[k] = root_w[k * 16 + cg];
    float4 br = make_float4(bih[cg] + bhh[cg], bih[cg + 16] + bhh[cg + 16],
                            bih[cg + 32] + bhh[cg + 32], bih[cg + 48] + bhh[cg + 48]);
    float4 bz = make_float4(bih[64 + cg] + bhh[64 + cg], bih[64 + cg + 16] + bhh[64 + cg + 16],
                            bih[64 + cg + 32] + bhh[64 + cg + 32], bih[64 + cg + 48] + bhh[64 + cg + 48]);
    float4 bni = make_float4(bih[128 + cg], bih[128 + cg + 16], bih[128 + cg + 32], bih[128 + cg + 48]);
    float4 bnh = make_float4(bhh[128 + cg], bhh[128 + cg + 16], bhh[128 + cg + 32], bhh[128 + cg + 48]);
    float cb = conv_b[cg];
    __syncthreads();

    int n0 = blockIdx.x * 128 + 8 * ng;
    float4 h_[8];
    float o2[8];
#pragma unroll
    for (int m = 0; m < 8; ++m) {
        int node = n0 + m;
        const float* hp = h + (size_t)node * 64 + cg;
        h_[m] = make_float4(hp[0], hp[16], hp[32], hp[48]);
        float o1 = out1[(size_t)node * 16 + cg];
        float acc = fmaf(aggr[(size_t)node * 16 + cg], inv_cnt[node], cb);
#pragma unroll
        for (int k = 0; k < 16; ++k) acc = fmaf(rw[k], __shfl(o1, lbase + k, 64), acc);
        o2[m] = acc;
    }
    float4 accr[8], accz[8], accn[8], accnh[8];
#pragma unroll
    for (int m = 0; m < 8; ++m) { accr[m] = br; accz[m] = bz; accn[m] = bni; accnh[m] = bnh; }

    // ih GEMM (k = 0..15), prefetched rolled loop
    {
        int wb = cg * 4;
        float4 wr = *(const float4*)&s_wih[wb];
        float4 wz = *(const float4*)&s_wih[wb + 64];
        float4 wn = *(const float4*)&s_wih[wb + 128];
        float xk[8], xkn[8];
#pragma unroll
        for (int m = 0; m < 8; ++m) xk[m] = __shfl(o2[m], lbase, 64);
#pragma unroll 1
        for (int k = 0; k < 15; ++k) {
            int b2 = (k + 1) * 196 + cg * 4;
            float4 wrn = *(const float4*)&s_wih[b2];
            float4 wzn = *(const float4*)&s_wih[b2 + 64];
            float4 wnn = *(const float4*)&s_wih[b2 + 128];
#pragma unroll
            for (int m = 0; m < 8; ++m) xkn[m] = __shfl(o2[m], lbase + k + 1, 64);
#pragma unroll
            for (int m = 0; m < 8; ++m) { FMA4(accr[m], xk[m], wr); FMA4(accz[m], xk[m], wz); FMA4(accn[m], xk[m], wn); }
            wr = wrn; wz = wzn; wn = wnn;
#pragma unroll
            for (int m = 0; m < 8; ++m) xk[m] = xkn[m];
        }
#pragma unroll
        for (int m = 0; m < 8; ++m) { FMA4(accr[m], xk[m], wr); FMA4(accz[m], xk[m], wz); FMA4(accn[m], xk[m], wn); }
    }

    // hh GEMM (d = 16*jj + dk), prefetched rolled inner loop
#pragma unroll
    for (int jj = 0; jj < 4; ++jj) {
        float hcur[8];
#pragma unroll
        for (int m = 0; m < 8; ++m)
            hcur[m] = (jj == 0) ? h_[m].x : (jj == 1) ? h_[m].y : (jj == 2) ? h_[m].z : h_[m].w;
        int wbase = (16 * jj) * 196 + cg * 4;
        float4 wr = *(const float4*)&s_whh[wbase];
        float4 wz = *(const float4*)&s_whh[wbase + 64];
        float4 wn = *(const float4*)&s_whh[wbase + 128];
        float hv[8], hvn[8];
#pragma unroll
        for (int m = 0; m < 8; ++m) hv[m] = __shfl(hcur[m], lbase, 64);
#pragma unroll 1
        for (int dk = 0; dk < 15; ++dk) {
            int b2 = wbase + (dk + 1) * 196;
            float4 wrn = *(const float4*)&s_whh[b2];
            float4 wzn = *(const float4*)&s_whh[b2 + 64];
            float4 wnn = *(const float4*)&s_whh[b2 + 128];
#pragma unroll
            for (int m = 0; m < 8; ++m) hvn[m] = __shfl(hcur[m], lbase + dk + 1, 64);
#pragma unroll
            for (int m = 0; m < 8; ++m) { FMA4(accr[m], hv[m], wr); FMA4(accz[m], hv[m], wz); FMA4(accnh[m], hv[m], wn); }
            wr = wrn; wz = wzn; wn = wnn;
#pragma unroll
            for (int m = 0; m < 8; ++m) hv[m] = hvn[m];
        }
#pragma unroll
        for (int m = 0; m < 8; ++m) { FMA4(accr[m], hv[m], wr); FMA4(accz[m], hv[m], wz); FMA4(accnh[m], hv[m], wn); }
    }

    // epilogue
#pragma unroll
    for (int m = 0; m < 8; ++m) {
        int node = n0 + m;
        float* hp = h + (size_t)node * 64 + cg;
#define GRU_OUT(J, HC, OFS) { \
        float r = 1.0f / (1.0f + __expf(-accr[m].J)); \
        float z = 1.0f / (1.0f + __expf(-accz[m].J)); \
        float x2 = fmaf(r, accnh[m].J, accn[m].J); \
        float ax = fabsf(x2); \
        float ee = __expf(-2.0f * ax); \
        float nc = __builtin_copysignf((1.0f - ee) / (1.0f + ee), x2); \
        hp[OFS] = fmaf(z, (HC) - nc, nc); }
        GRU_OUT(x, h_[m].x, 0)
        GRU_OUT(y, h_[m].y, 16)
        GRU_OUT(z, h_[m].z, 32)
        GRU_OUT(w, h_[m].w, 48)
#undef GRU_OUT
    }
}

// ---------------- final: y = h @ lin2_w ; pooled = segment_sum(y, batch) ----------------
__global__ __launch_bounds__(256) void k_final(const float* __restrict__ h, const float* __restrict__ w2,
                                               const int* __restrict__ batch, float* __restrict__ out) {
    int i = blockIdx.x * 4 + (threadIdx.x >> 6);
    int lane = threadIdx.x & 63;
    float v = h[(size_t)i * DIM + lane] * w2[lane];
#pragma unroll
    for (int off = 32; off > 0; off >>= 1) v += __shfl_down(v, off, 64);
    if (lane == 0) atomicAdd(&out[batch[i]], v);
}

extern "C" void kernel_launch(void* const* d_in, const int* in_sizes, int n_in,
                              void* d_out, int out_size, void* d_ws, size_t ws_size,
                              hipStream_t stream) {
    const float* x        = (const float*)d_in[0];
    const float* edge_attr= (const float*)d_in[1];
    const float* lin0_w   = (const float*)d_in[2];
    const float* lin0_b   = (const float*)d_in[3];
    const float* nn1_w    = (const float*)d_in[4];
    const float* nn1_b    = (const float*)d_in[5];
    const float* root_w   = (const float*)d_in[6];
    const float* conv_b   = (const float*)d_in[7];
    const float* gru_w_ih = (const float*)d_in[8];
    const float* gru_w_hh = (const float*)d_in[9];
    const float* gru_b_ih = (const float*)d_in[10];
    const float* gru_b_hh = (const float*)d_in[11];
    const float* lin1_w   = (const float*)d_in[12];
    const float* lin1_b   = (const float*)d_in[13];
    const float* lin2_w   = (const float*)d_in[14];
    const int*   ei       = (const int*)d_in[15];
    const int*   batch    = (const int*)d_in[16];
    float* out = (float*)d_out;

    // workspace layout (f32): h[N*64] | out1[N*16] | aggr[N*16] | inv_cnt[N]
    char* ws = (char*)d_ws;
    float* h       = (float*)(ws);
    float* out1    = (float*)(ws + (size_t)N_NODES * DIM * 4);
    float* aggr    = (float*)(ws + (size_t)N_NODES * DIM * 4 + (size_t)N_NODES * DNN * 4);
    float* inv_cnt = (float*)(ws + (size_t)N_NODES * DIM * 4 + 2ull * N_NODES * DNN * 4);

    hipMemsetAsync(d_out, 0, (size_t)NG * 4, stream);
    hipMemsetAsync(inv_cnt, 0, (size_t)N_NODES * 4, stream);
    k_degree<<<N_EDGES / 256, 256, 0, stream>>>(ei, inv_cnt);
    k_invcnt<<<N_NODES / 256, 256, 0, stream>>>(inv_cnt);
    k_init<<<N_NODES * DIM / 256, 256, 0, stream>>>(x, lin0_w, lin0_b, h);

    for (int it = 0; it < N_ITERS; ++it) {
        int j = it >> 1;   // GRU index (NL2 = 2)
        k_lin1<<<N_NODES / 64, 256, 0, stream>>>(h, lin1_w, lin1_b, out1, aggr);
        k_edge<<<2048, 256, 0, stream>>>(out1, edge_attr, ei, nn1_w, nn1_b, aggr);
        k_node<<<N_NODES / 128, 256, 0, stream>>>(out1, aggr, inv_cnt, h, root_w, conv_b,
                                         gru_w_ih + (size_t)j * 192 * DNN,
                                         gru_w_hh + (size_t)j * 192 * DIM,
                                         gru_b_ih + (size_t)j * 192,
                                         gru_b_hh + (size_t)j * 192);
    }
    k_final<<<N_NODES / 4, 256, 0, stream>>>(h, lin2_w, batch, out);
}